// Round 7
// baseline (975.414 us; speedup 1.0000x reference)
//
#include <hip/hip_runtime.h>
#include <hip/hip_cooperative_groups.h>
#include <cstdint>
#include <cstddef>

namespace cg = cooperative_groups;

#define N_NODES 8192
#define NFEAT   512
#define NHID    128
#define NTHR    256

typedef unsigned short u16;
typedef __attribute__((ext_vector_type(8))) short bf16x8;
typedef __attribute__((ext_vector_type(4))) float f32x4;

__device__ inline u16 f2bf(float f) {
    unsigned int u = __float_as_uint(f);
    unsigned int r = (u + 0x7FFFu + ((u >> 16) & 1u)) >> 16;
    return (u16)r;
}
__device__ inline float bf2f(u16 h) {
    return __uint_as_float(((unsigned int)h) << 16);
}

struct Params {
    const float* x;
    const int*   ei;
    const int*   t;
    const float *gcW, *gcB, *gctW, *gctB, *avec;
    const float *ppW, *ppB, *pp2W, *pp2B;
    const float *t00W, *t00B, *t10W, *t10B, *t01W, *t01B, *t11W, *t11B;
    unsigned int* bitmap;
    int*   cnt;
    u16*   rep_preh;
    float* rep;
    u16*   rep_t_h;
    float* u;
    float* v;
    int*   rowptr;
    int*   colidx;
    float* colpart;   // [nblk][128]
    float* colpart2;  // [128][128]
    float* colsum;    // [128]  (fallback path only)
    float* y_out;
    float* hp_out;
    float* tr_out;
    int    E;
};

// ============================ MEGA v2 (cooperative) =========================
// Dynamic grid: nblk = gridDim.x in {512, 1024, 2048}; rows_pb = 8192/nblk.
__global__ __launch_bounds__(NTHR, 8)
void mega(Params p)
{
    cg::grid_group grid = cg::this_grid();
    const int bid = blockIdx.x;
    const int tid = threadIdx.x;
    const int nblk = gridDim.x;
    const int rows_pb = N_NODES / nblk;

    __shared__ __align__(16) union {
        struct { u16 A[64][40]; u16 B[64][40]; } gm;                          // 10240 B
        struct { int part[256]; int rowoff[17]; } sc;
        struct { float su[256]; float sv[256]; } ag;
        struct { float red[2][128]; float wsh[2][128]; int csh[2][128]; } at;
        struct { float hs[8][128]; float ts[8][128]; float fin[2][2][4][4]; } hd;
    } sh;

    // =================== Phase A: zero bitmap+cnt; GEMM =====================
    {
        uint4* z16 = (uint4*)p.bitmap;            // bitmap+cnt contiguous
        const int n16 = (8388608 + 32768) / 16;
        const uint4 z = make_uint4(0u, 0u, 0u, 0u);
        for (int i = bid * NTHR + tid; i < n16; i += nblk * NTHR) z16[i] = z;
    }
    for (int tile = bid; tile < 512; tile += nblk) {
        // rep_preh = bf16(x @ [gcW | gctW]); 512 tiles of 64x64
        const int bx   = tile & 3;
        const int by   = tile >> 2;
        const int lane = tid & 63;
        const int wid  = tid >> 6;
        const int wr   = wid >> 1, wc = wid & 1;
        const float* W = (bx < 2) ? p.gcW : p.gctW;
        const int n0w  = (bx & 1) * 64;
        const int row0 = by * 64;

        f32x4 acc[2][2];
#pragma unroll
        for (int i = 0; i < 2; ++i)
#pragma unroll
            for (int j = 0; j < 2; ++j) acc[i][j] = (f32x4){0.f, 0.f, 0.f, 0.f};

        const int sr = tid >> 2;
        const int sq = tid & 3;
        const int fr = lane & 15;
        const int fq = lane >> 4;

        for (int k0 = 0; k0 < NFEAT; k0 += 32) {
            {   // stage A tile
                const float* src = p.x + (size_t)(row0 + sr) * NFEAT + k0 + sq * 8;
                const float4 a0 = *reinterpret_cast<const float4*>(src);
                const float4 a1 = *reinterpret_cast<const float4*>(src + 4);
                union { u16 s[8]; bf16x8 v; } pk;
                pk.s[0] = f2bf(a0.x); pk.s[1] = f2bf(a0.y);
                pk.s[2] = f2bf(a0.z); pk.s[3] = f2bf(a0.w);
                pk.s[4] = f2bf(a1.x); pk.s[5] = f2bf(a1.y);
                pk.s[6] = f2bf(a1.z); pk.s[7] = f2bf(a1.w);
                *reinterpret_cast<bf16x8*>(&sh.gm.A[sr][sq * 8]) = pk.v;
            }
            {   // stage B tile transposed
                const float* wsrc = W + (size_t)(k0 + sq * 8) * NHID + n0w + sr;
                union { u16 s[8]; bf16x8 v; } pk;
#pragma unroll
                for (int j = 0; j < 8; ++j)
                    pk.s[j] = f2bf(wsrc[(size_t)j * NHID]);
                *reinterpret_cast<bf16x8*>(&sh.gm.B[sr][sq * 8]) = pk.v;
            }
            __syncthreads();
            const bf16x8 a0 = *reinterpret_cast<const bf16x8*>(&sh.gm.A[wr * 32 + fr][fq * 8]);
            const bf16x8 a1 = *reinterpret_cast<const bf16x8*>(&sh.gm.A[wr * 32 + 16 + fr][fq * 8]);
            const bf16x8 b0 = *reinterpret_cast<const bf16x8*>(&sh.gm.B[wc * 32 + fr][fq * 8]);
            const bf16x8 b1 = *reinterpret_cast<const bf16x8*>(&sh.gm.B[wc * 32 + 16 + fr][fq * 8]);
            acc[0][0] = __builtin_amdgcn_mfma_f32_16x16x32_bf16(a0, b0, acc[0][0], 0, 0, 0);
            acc[0][1] = __builtin_amdgcn_mfma_f32_16x16x32_bf16(a0, b1, acc[0][1], 0, 0, 0);
            acc[1][0] = __builtin_amdgcn_mfma_f32_16x16x32_bf16(a1, b0, acc[1][0], 0, 0, 0);
            acc[1][1] = __builtin_amdgcn_mfma_f32_16x16x32_bf16(a1, b1, acc[1][1], 0, 0, 0);
            __syncthreads();
        }
        const int gr = row0 + wr * 32 + fq * 4;
        const int gc = bx * 64 + wc * 32 + fr;
#pragma unroll
        for (int mi = 0; mi < 2; ++mi)
#pragma unroll
            for (int ni = 0; ni < 2; ++ni)
#pragma unroll
                for (int i = 0; i < 4; ++i)
                    p.rep_preh[(size_t)(gr + mi * 16 + i) * 256 + gc + ni * 16] =
                        f2bf(acc[mi][ni][i]);
    }
    grid.sync();

    // =================== Phase B: edge dedup (atomics) ======================
    for (int e = bid * NTHR + tid; e < p.E; e += nblk * NTHR) {
        const int s = p.ei[e];
        const int d = p.ei[p.E + e];
        const unsigned int idx  = (unsigned int)s * 8192u + (unsigned int)d;
        const unsigned int mask = 1u << (idx & 31u);
        const unsigned int old  = atomicOr(&p.bitmap[idx >> 5], mask);
        if ((old & mask) == 0u) atomicAdd(&p.cnt[s], 1);
    }
    grid.sync();

    // ======= Phase C: redundant scan -> rowptr; bitmap -> sorted colidx =====
    {
        int ssum = 0;
        const int cb = tid * 32;
#pragma unroll
        for (int j = 0; j < 32; ++j) ssum += p.cnt[cb + j];
        sh.sc.part[tid] = ssum;
        __syncthreads();
        for (int off = 1; off < 256; off <<= 1) {
            const int val = (tid >= off) ? sh.sc.part[tid - off] : 0;
            __syncthreads();
            sh.sc.part[tid] += val;
            __syncthreads();
        }
        if (tid == 0) {
            const int R0 = bid * rows_pb;
            const int chunk = R0 >> 5;
            int off = (chunk == 0) ? 0 : sh.sc.part[chunk - 1];
            const int skip = R0 & 31;
            for (int j = 0; j < skip; ++j) off += p.cnt[chunk * 32 + j];
            for (int j = 0; j < rows_pb; ++j) {
                sh.sc.rowoff[j] = off;
                p.rowptr[R0 + j] = off;
                off += p.cnt[R0 + j];
            }
            sh.sc.rowoff[rows_pb] = off;
            if (bid == nblk - 1) p.rowptr[N_NODES] = off;
        }
        __syncthreads();
        // extract: 4 waves, wave wv handles rows lrow = wv, wv+4, ...
        const int wv = tid >> 6, lane = tid & 63;
        for (int lrow = wv; lrow < rows_pb; lrow += 4) {
            const int row  = bid * rows_pb + lrow;
            const uint4 w4 = *reinterpret_cast<const uint4*>(
                p.bitmap + (size_t)row * 256 + lane * 4);
            const int c = __popc(w4.x) + __popc(w4.y) + __popc(w4.z) + __popc(w4.w);
            int off = c;
            for (int d = 1; d < 64; d <<= 1) {
                const int n = __shfl_up(off, d, 64);
                if (lane >= d) off += n;
            }
            off -= c;
            int pos = sh.sc.rowoff[lrow] + off;
            const int base = lane * 128;
            unsigned int wvv[4] = {w4.x, w4.y, w4.z, w4.w};
#pragma unroll
            for (int j = 0; j < 4; ++j) {
                unsigned int b = wvv[j];
                while (b) {
                    const int bit = __ffs(b) - 1;
                    p.colidx[pos++] = base + j * 32 + bit;
                    b &= b - 1;
                }
            }
        }
    }
    grid.sync();

    // ========== Phase D: aggregate + bias + relu; u,v; colsum partials ======
    {
        float csloc = 0.f;
        for (int rr = 0; rr < rows_pb; ++rr) {
            const int i  = bid * rows_pb + rr;
            const int rp = p.rowptr[i], rpe = p.rowptr[i + 1];
            float acc = 0.f;
            for (int q = rp; q < rpe; ++q)
                acc += bf2f(p.rep_preh[(size_t)p.colidx[q] * 256 + tid]);
            const float bias = (tid < 128) ? p.gcB[tid] : p.gctB[tid - 128];
            const float val  = fmaxf(acc + bias, 0.f);
            p.rep[(size_t)i * 256 + tid] = val;
            if (tid >= 128) {
                p.rep_t_h[(size_t)i * 128 + tid - 128] = f2bf(val);
                csloc += val;
            }
            sh.ag.su[tid] = p.avec[tid] * val;
            sh.ag.sv[tid] = p.avec[256 + tid] * val;
            __syncthreads();
#pragma unroll
            for (int s = 128; s > 0; s >>= 1) {
                if (tid < s) { sh.ag.su[tid] += sh.ag.su[tid + s];
                               sh.ag.sv[tid] += sh.ag.sv[tid + s]; }
                __syncthreads();
            }
            if (tid == 0) { p.u[i] = sh.ag.su[0]; p.v[i] = sh.ag.sv[0]; }
            __syncthreads();
        }
        if (tid >= 128) p.colpart[(size_t)bid * 128 + tid - 128] = csloc;
    }
    grid.sync();

    // ============ Phase D2: colsum partial fold (128 blocks) ================
    if (bid < 128 && tid < 128) {
        const int gpb = nblk >> 7;   // nblk/128
        float s = 0.f;
        for (int k = 0; k < gpb; ++k)
            s += p.colpart[(size_t)(bid * gpb + k) * 128 + tid];
        p.colpart2[(size_t)bid * 128 + tid] = s;
    }
    grid.sync();

    // =================== Phase E: attention (2 rows per pass) ===============
    {
        const int h = tid >> 7, f = tid & 127;
        // redundant deterministic colsum from the 128 partials (L2-hot)
        float csum = 0.f;
        for (int j = 0; j < 128; ++j) csum += p.colpart2[(size_t)j * 128 + f];

        for (int pr = 0; pr < rows_pb / 2; ++pr) {
            const int rbase = bid * rows_pb + pr * 2;
            const int rpA = p.rowptr[rbase];
            const int rpB = p.rowptr[rbase + 1];
            const int rpC = p.rowptr[rbase + 2];
            const int degA = rpB - rpA, degB = rpC - rpB;
            const int row  = rbase + h;
            const int rp   = h ? rpB : rpA;
            const int deg  = h ? degB : degA;
            const int maxdeg = max(degA, degB);
            const float ui = p.u[row];

            float mloc = -1e30f;
            for (int q = f; q < deg; q += 128)
                mloc = fmaxf(mloc, ui + p.v[p.colidx[rp + q]]);
            sh.at.red[h][f] = mloc;
            __syncthreads();
#pragma unroll
            for (int s = 64; s > 0; s >>= 1) {
                if (f < s) sh.at.red[h][f] = fmaxf(sh.at.red[h][f], sh.at.red[h][f + s]);
                __syncthreads();
            }
            const float m = fmaxf(sh.at.red[h][0], 0.f);
            __syncthreads();
            const float e0 = expf(-m);

            float Zloc = 0.f, acc = 0.f;
            const int rounds = (maxdeg + 127) >> 7;
            for (int b2 = 0; b2 < rounds; ++b2) {
                const int q = b2 * 128 + f;
                if (q < deg) {
                    const int c = p.colidx[rp + q];
                    sh.at.csh[h][f] = c;
                    const float w = expf(ui + p.v[c] - m);
                    sh.at.wsh[h][f] = w;
                    Zloc += w;
                }
                __syncthreads();
                const int cnt2 = min(128, deg - b2 * 128);
                for (int q2 = 0; q2 < cnt2; ++q2)
                    acc += (sh.at.wsh[h][q2] - e0) *
                           bf2f(p.rep_t_h[(size_t)sh.at.csh[h][q2] * 128 + f]);
                __syncthreads();
            }
            sh.at.red[h][f] = Zloc;
            __syncthreads();
#pragma unroll
            for (int s = 64; s > 0; s >>= 1) {
                if (f < s) sh.at.red[h][f] += sh.at.red[h][f + s];
                __syncthreads();
            }
            const float Z  = sh.at.red[h][0] + (8192.f - (float)deg) * e0;
            const float hv = (acc + e0 * csum) / Z + p.rep[(size_t)row * 256 + f];
            p.hp_out[(size_t)row * 128 + f] = hv;
            __syncthreads();
        }
    }
    grid.sync();

    // =================== Phase F: output heads (8-row groups) ===============
    for (int g0 = bid; g0 < N_NODES / 8; g0 += nblk) {
        const int f = tid & 127, h = tid >> 7;
        const int r0 = g0 * 8;
        __syncthreads();
#pragma unroll
        for (int r = 0; r < 4; ++r) {
            sh.hd.hs[h * 4 + r][f] = p.hp_out[(size_t)(r0 + h * 4 + r) * 128 + f];
            sh.hd.ts[h * 4 + r][f] = p.rep[(size_t)(r0 + h * 4 + r) * 256 + 128 + f];
        }
        __syncthreads();

        float a00[4] = {0,0,0,0}, a10[4] = {0,0,0,0}, app[4] = {0,0,0,0};
        for (int k = 0; k < 128; ++k) {
            const float w00 = p.t00W[k * 128 + f];
            const float w10 = p.t10W[k * 128 + f];
            const float wpp = p.ppW [k * 128 + f];
#pragma unroll
            for (int r = 0; r < 4; ++r) {
                a00[r] += sh.hd.hs[h * 4 + r][k] * w00;
                a10[r] += sh.hd.hs[h * 4 + r][k] * w10;
                app[r] += sh.hd.ts[h * 4 + r][k] * wpp;
            }
        }
        const float b00 = p.t00B[f], b10 = p.t10B[f], bpp = p.ppB[f];
        const float w01 = p.t01W[f], w11 = p.t11W[f];
        const float w20 = p.pp2W[2 * f + 0], w21 = p.pp2W[2 * f + 1];
        const int lane = tid & 63, wih = (tid >> 6) & 1;
#pragma unroll
        for (int r = 0; r < 4; ++r) {
            float s0 = fmaxf(a00[r] + b00, 0.f) * w01;
            float s1 = fmaxf(a10[r] + b10, 0.f) * w11;
            const float hp2 = app[r] + bpp;
            float s2 = hp2 * w20;
            float s3 = hp2 * w21;
#pragma unroll
            for (int off = 32; off > 0; off >>= 1) {
                s0 += __shfl_down(s0, off, 64);
                s1 += __shfl_down(s1, off, 64);
                s2 += __shfl_down(s2, off, 64);
                s3 += __shfl_down(s3, off, 64);
            }
            if (lane == 0) {
                sh.hd.fin[h][wih][r][0] = s0;
                sh.hd.fin[h][wih][r][1] = s1;
                sh.hd.fin[h][wih][r][2] = s2;
                sh.hd.fin[h][wih][r][3] = s3;
            }
        }
        __syncthreads();
        if (tid < 8) {
            const int hh = tid >> 2, rr = tid & 3;
            const int node = r0 + hh * 4 + rr;
            const float y0 = sh.hd.fin[hh][0][rr][0] + sh.hd.fin[hh][1][rr][0] + p.t01B[0];
            const float y1 = sh.hd.fin[hh][0][rr][1] + sh.hd.fin[hh][1][rr][1] + p.t11B[0];
            p.y_out[node] = (p.t[node] > 0) ? y1 : y0;
            const float tr0 = sh.hd.fin[hh][0][rr][2] + sh.hd.fin[hh][1][rr][2] + p.pp2B[0];
            const float tr1 = sh.hd.fin[hh][0][rr][3] + sh.hd.fin[hh][1][rr][3] + p.pp2B[1];
            p.tr_out[node * 2 + 0] = 1.f / (1.f + expf(-tr0));
            p.tr_out[node * 2 + 1] = 1.f / (1.f + expf(-tr1));
        }
    }
}

// ===================== FALLBACK kernels (round-4 pipeline) ==================
__global__ __launch_bounds__(256)
void zero_ws(uint4* __restrict__ p, int n16)
{
    const uint4 z = make_uint4(0u, 0u, 0u, 0u);
    for (int i = blockIdx.x * blockDim.x + threadIdx.x; i < n16;
         i += gridDim.x * blockDim.x)
        p[i] = z;
}

__global__ __launch_bounds__(256)
void gemm_mfma(const float* __restrict__ x,
               const float* __restrict__ gcW,
               const float* __restrict__ gctW,
               u16* __restrict__ rep_preh)
{
    const int bx   = blockIdx.x;
    const int by   = blockIdx.y;
    const int tid  = threadIdx.x;
    const int lane = tid & 63;
    const int wid  = tid >> 6;
    const int wr   = wid >> 1, wc = wid & 1;
    const float* W = (bx < 2) ? gcW : gctW;
    const int n0w  = (bx & 1) * 64;
    const int row0 = by * 64;

    __shared__ __align__(16) u16 Ash[64][40];
    __shared__ __align__(16) u16 Bsh[64][40];

    f32x4 acc[2][2];
#pragma unroll
    for (int i = 0; i < 2; ++i)
#pragma unroll
        for (int j = 0; j < 2; ++j) acc[i][j] = (f32x4){0.f, 0.f, 0.f, 0.f};

    const int sr = tid >> 2;
    const int sq = tid & 3;
    const int fr = lane & 15;
    const int fq = lane >> 4;

    for (int k0 = 0; k0 < NFEAT; k0 += 32) {
        {
            const float* src = x + (size_t)(row0 + sr) * NFEAT + k0 + sq * 8;
            const float4 a0 = *reinterpret_cast<const float4*>(src);
            const float4 a1 = *reinterpret_cast<const float4*>(src + 4);
            union { u16 s[8]; bf16x8 v; } pk;
            pk.s[0] = f2bf(a0.x); pk.s[1] = f2bf(a0.y);
            pk.s[2] = f2bf(a0.z); pk.s[3] = f2bf(a0.w);
            pk.s[4] = f2bf(a1.x); pk.s[5] = f2bf(a1.y);
            pk.s[6] = f2bf(a1.z); pk.s[7] = f2bf(a1.w);
            *reinterpret_cast<bf16x8*>(&Ash[sr][sq * 8]) = pk.v;
        }
        {
            const float* wsrc = W + (size_t)(k0 + sq * 8) * NHID + n0w + sr;
            union { u16 s[8]; bf16x8 v; } pk;
#pragma unroll
            for (int j = 0; j < 8; ++j)
                pk.s[j] = f2bf(wsrc[(size_t)j * NHID]);
            *reinterpret_cast<bf16x8*>(&Bsh[sr][sq * 8]) = pk.v;
        }
        __syncthreads();
        const bf16x8 a0 = *reinterpret_cast<const bf16x8*>(&Ash[wr * 32 + fr][fq * 8]);
        const bf16x8 a1 = *reinterpret_cast<const bf16x8*>(&Ash[wr * 32 + 16 + fr][fq * 8]);
        const bf16x8 b0 = *reinterpret_cast<const bf16x8*>(&Bsh[wc * 32 + fr][fq * 8]);
        const bf16x8 b1 = *reinterpret_cast<const bf16x8*>(&Bsh[wc * 32 + 16 + fr][fq * 8]);
        acc[0][0] = __builtin_amdgcn_mfma_f32_16x16x32_bf16(a0, b0, acc[0][0], 0, 0, 0);
        acc[0][1] = __builtin_amdgcn_mfma_f32_16x16x32_bf16(a0, b1, acc[0][1], 0, 0, 0);
        acc[1][0] = __builtin_amdgcn_mfma_f32_16x16x32_bf16(a1, b0, acc[1][0], 0, 0, 0);
        acc[1][1] = __builtin_amdgcn_mfma_f32_16x16x32_bf16(a1, b1, acc[1][1], 0, 0, 0);
        __syncthreads();
    }
    const int gr = row0 + wr * 32 + fq * 4;
    const int gc = bx * 64 + wc * 32 + fr;
#pragma unroll
    for (int mi = 0; mi < 2; ++mi)
#pragma unroll
        for (int ni = 0; ni < 2; ++ni)
#pragma unroll
            for (int i = 0; i < 4; ++i)
                rep_preh[(size_t)(gr + mi * 16 + i) * 256 + gc + ni * 16] =
                    f2bf(acc[mi][ni][i]);
}

__global__ void edge_pass1(const int* __restrict__ ei, int E,
                           unsigned int* __restrict__ bitmap,
                           int* __restrict__ cnt)
{
    const int e = blockIdx.x * blockDim.x + threadIdx.x;
    if (e >= E) return;
    const int s = ei[e];
    const int d = ei[E + e];
    const unsigned int idx  = (unsigned int)s * 8192u + (unsigned int)d;
    const unsigned int mask = 1u << (idx & 31u);
    const unsigned int old  = atomicOr(&bitmap[idx >> 5], mask);
    if ((old & mask) == 0u) atomicAdd(&cnt[s], 1);
}

__global__ __launch_bounds__(1024)
void scan_kernel(const int* __restrict__ cnt, int* __restrict__ rowptr)
{
    __shared__ int part[1024];
    const int tid = threadIdx.x;
    int loc[8];
    int s = 0;
#pragma unroll
    for (int j = 0; j < 8; ++j) { loc[j] = cnt[tid * 8 + j]; s += loc[j]; }
    part[tid] = s;
    __syncthreads();
    for (int off = 1; off < 1024; off <<= 1) {
        const int val = (tid >= off) ? part[tid - off] : 0;
        __syncthreads();
        part[tid] += val;
        __syncthreads();
    }
    int run = (tid == 0) ? 0 : part[tid - 1];
#pragma unroll
    for (int j = 0; j < 8; ++j) { rowptr[tid * 8 + j] = run; run += loc[j]; }
    if (tid == 1023) rowptr[8192] = run;
}

__global__ __launch_bounds__(64)
void bitmap_extract(const unsigned int* __restrict__ bitmap,
                    const int* __restrict__ rowptr,
                    int* __restrict__ colidx)
{
    const int row  = blockIdx.x;
    const int lane = threadIdx.x;
    const uint4 w = *reinterpret_cast<const uint4*>(
        bitmap + (size_t)row * 256 + lane * 4);
    const int c = __popc(w.x) + __popc(w.y) + __popc(w.z) + __popc(w.w);
    int off = c;
    for (int d = 1; d < 64; d <<= 1) {
        const int n = __shfl_up(off, d, 64);
        if (lane >= d) off += n;
    }
    off -= c;
    int pos = rowptr[row] + off;
    const int base = lane * 128;
    unsigned int wv[4] = {w.x, w.y, w.z, w.w};
#pragma unroll
    for (int j = 0; j < 4; ++j) {
        unsigned int b = wv[j];
        while (b) {
            const int bit = __ffs(b) - 1;
            colidx[pos++] = base + j * 32 + bit;
            b &= b - 1;
        }
    }
}

__global__ __launch_bounds__(256)
void aggregate_kernel(const u16* __restrict__ rep_preh,
                      const int* __restrict__ rowptr,
                      const int* __restrict__ colidx,
                      const float* __restrict__ gcB,
                      const float* __restrict__ gctB,
                      const float* __restrict__ avec,
                      float* __restrict__ rep,
                      u16* __restrict__ rep_t_h,
                      float* __restrict__ u,
                      float* __restrict__ v)
{
    const int i   = blockIdx.x;
    const int tid = threadIdx.x;
    const int rp  = rowptr[i];
    const int rpe = rowptr[i + 1];
    float acc = 0.f;
    for (int p = rp; p < rpe; ++p)
        acc += bf2f(rep_preh[(size_t)colidx[p] * 256 + tid]);
    const float bias = (tid < 128) ? gcB[tid] : gctB[tid - 128];
    const float val  = fmaxf(acc + bias, 0.f);
    rep[(size_t)i * 256 + tid] = val;
    if (tid >= 128) rep_t_h[(size_t)i * 128 + tid - 128] = f2bf(val);

    __shared__ float su[256], sv[256];
    su[tid] = avec[tid] * val;
    sv[tid] = avec[256 + tid] * val;
    __syncthreads();
#pragma unroll
    for (int s = 128; s > 0; s >>= 1) {
        if (tid < s) { su[tid] += su[tid + s]; sv[tid] += sv[tid + s]; }
        __syncthreads();
    }
    if (tid == 0) { u[i] = su[0]; v[i] = sv[0]; }
}

__global__ __launch_bounds__(128)
void colsum_kernel(const u16* __restrict__ rep_t_h, float* __restrict__ colpart)
{
    const int f = threadIdx.x;
    const int b = blockIdx.x;
    const int r0 = b * 32;
    float s = 0.f;
    for (int r = 0; r < 32; ++r)
        s += bf2f(rep_t_h[(size_t)(r0 + r) * 128 + f]);
    colpart[b * 128 + f] = s;
}

__global__ __launch_bounds__(128)
void colsum_final(const float* __restrict__ colpart, float* __restrict__ colsum)
{
    const int f = threadIdx.x;
    float s = 0.f;
    for (int b = 0; b < 256; ++b) s += colpart[b * 128 + f];
    colsum[f] = s;
}

__global__ __launch_bounds__(128)
void attention_kernel(const int* __restrict__ rowptr,
                      const int* __restrict__ colidx,
                      const float* __restrict__ u,
                      const float* __restrict__ v,
                      const u16* __restrict__ rep_t_h,
                      const float* __restrict__ rep,
                      const float* __restrict__ colsum,
                      float* __restrict__ hp_out)
{
    const int i   = blockIdx.x;
    const int tid = threadIdx.x;
    const int rp  = rowptr[i];
    const int deg = rowptr[i + 1] - rp;
    const float ui = u[i];

    __shared__ float red[128];
    __shared__ float wsh[128];
    __shared__ int   csh[128];

    float mloc = -1e30f;
    for (int p = tid; p < deg; p += 128)
        mloc = fmaxf(mloc, ui + v[colidx[rp + p]]);
    red[tid] = mloc;
    __syncthreads();
#pragma unroll
    for (int s = 64; s > 0; s >>= 1) {
        if (tid < s) red[tid] = fmaxf(red[tid], red[tid + s]);
        __syncthreads();
    }
    const float m = fmaxf(red[0], 0.f);
    __syncthreads();
    const float e0 = expf(-m);

    float Zloc = 0.f;
    float acc  = 0.f;
    for (int base = 0; base < deg; base += 128) {
        const int p = base + tid;
        if (p < deg) {
            const int c = colidx[rp + p];
            csh[tid] = c;
            const float w = expf(ui + v[c] - m);
            wsh[tid] = w;
            Zloc += w;
        }
        __syncthreads();
        const int cnt2 = min(128, deg - base);
        for (int q = 0; q < cnt2; ++q)
            acc += (wsh[q] - e0) * bf2f(rep_t_h[(size_t)csh[q] * 128 + tid]);
        __syncthreads();
    }
    red[tid] = Zloc;
    __syncthreads();
#pragma unroll
    for (int s = 64; s > 0; s >>= 1) {
        if (tid < s) red[tid] += red[tid + s];
        __syncthreads();
    }
    const float Z  = red[0] + (8192.f - (float)deg) * e0;
    const float hv = (acc + e0 * colsum[tid]) / Z + rep[(size_t)i * 256 + tid];
    hp_out[(size_t)i * 128 + tid] = hv;
}

__global__ __launch_bounds__(128)
void heads_kernel(const float* __restrict__ hprime,
                  const float* __restrict__ rep,
                  const int* __restrict__ t,
                  const float* __restrict__ ppW,  const float* __restrict__ ppB,
                  const float* __restrict__ pp2W, const float* __restrict__ pp2B,
                  const float* __restrict__ t00W, const float* __restrict__ t00B,
                  const float* __restrict__ t10W, const float* __restrict__ t10B,
                  const float* __restrict__ t01W, const float* __restrict__ t01B,
                  const float* __restrict__ t11W, const float* __restrict__ t11B,
                  float* __restrict__ y_out,
                  float* __restrict__ treat_out)
{
    const int f  = threadIdx.x;
    const int r0 = blockIdx.x * 8;
    __shared__ float hs[8][128];
    __shared__ float ts[8][128];
#pragma unroll
    for (int r = 0; r < 8; ++r) {
        hs[r][f] = hprime[(size_t)(r0 + r) * 128 + f];
        ts[r][f] = rep[(size_t)(r0 + r) * 256 + 128 + f];
    }
    __syncthreads();

    float a00[8], a10[8], app[8];
#pragma unroll
    for (int r = 0; r < 8; ++r) { a00[r] = 0.f; a10[r] = 0.f; app[r] = 0.f; }

    for (int k = 0; k < 128; ++k) {
        const float w00 = t00W[k * 128 + f];
        const float w10 = t10W[k * 128 + f];
        const float wpp = ppW [k * 128 + f];
#pragma unroll
        for (int r = 0; r < 8; ++r) {
            a00[r] += hs[r][k] * w00;
            a10[r] += hs[r][k] * w10;
            app[r] += ts[r][k] * wpp;
        }
    }
    __syncthreads();

    const float b00 = t00B[f], b10 = t10B[f], bpp = ppB[f];
    const float w01 = t01W[f], w11 = t11W[f];
    const float w20 = pp2W[2 * f + 0], w21 = pp2W[2 * f + 1];

    for (int r = 0; r < 8; ++r) {
        __syncthreads();
        const float h00 = fmaxf(a00[r] + b00, 0.f);
        const float h10 = fmaxf(a10[r] + b10, 0.f);
        const float hp2 = app[r] + bpp;
        hs[0][f] = h00 * w01;
        hs[1][f] = h10 * w11;
        hs[2][f] = hp2 * w20;
        hs[3][f] = hp2 * w21;
        __syncthreads();
#pragma unroll
        for (int s = 64; s > 0; s >>= 1) {
            if (f < s) {
                hs[0][f] += hs[0][f + s];
                hs[1][f] += hs[1][f + s];
                hs[2][f] += hs[2][f + s];
                hs[3][f] += hs[3][f + s];
            }
            __syncthreads();
        }
        if (f == 0) {
            const int node = r0 + r;
            const float y0 = hs[0][0] + t01B[0];
            const float y1 = hs[1][0] + t11B[0];
            y_out[node] = (t[node] > 0) ? y1 : y0;
            const float tr0 = hs[2][0] + pp2B[0];
            const float tr1 = hs[3][0] + pp2B[1];
            treat_out[node * 2 + 0] = 1.f / (1.f + expf(-tr0));
            treat_out[node * 2 + 1] = 1.f / (1.f + expf(-tr1));
        }
    }
}

// ===========================================================================
extern "C" void kernel_launch(void* const* d_in, const int* in_sizes, int n_in,
                              void* d_out, int out_size, void* d_ws, size_t ws_size,
                              hipStream_t stream)
{
    char* ws = (char*)d_ws;

    Params prm;
    prm.x    = (const float*)d_in[0];
    // d_in[1] = dense adj : intentionally unused
    prm.ei   = (const int*)d_in[2];
    prm.t    = (const int*)d_in[3];
    prm.gcW  = (const float*)d_in[4];
    prm.gcB  = (const float*)d_in[5];
    prm.gctW = (const float*)d_in[6];
    prm.gctB = (const float*)d_in[7];
    prm.avec = (const float*)d_in[8];
    prm.ppW  = (const float*)d_in[9];
    prm.ppB  = (const float*)d_in[10];
    prm.pp2W = (const float*)d_in[11];
    prm.pp2B = (const float*)d_in[12];
    prm.t00W = (const float*)d_in[13];
    prm.t00B = (const float*)d_in[14];
    prm.t10W = (const float*)d_in[15];
    prm.t10B = (const float*)d_in[16];
    prm.t01W = (const float*)d_in[17];
    prm.t01B = (const float*)d_in[18];
    prm.t11W = (const float*)d_in[19];
    prm.t11B = (const float*)d_in[20];

    prm.bitmap   = (unsigned int*)(ws + 0);
    prm.cnt      = (int*)   (ws + 8388608);
    prm.rep_preh = (u16*)   (ws + 8421376);
    prm.rep      = (float*) (ws + 12615680);
    prm.rep_t_h  = (u16*)   (ws + 21004288);
    prm.u        = (float*) (ws + 23101440);
    prm.v        = (float*) (ws + 23134208);
    prm.rowptr   = (int*)   (ws + 23166976);
    prm.colidx   = (int*)   (ws + 23200256);
    prm.colpart  = (float*) (ws + 24248832);   // up to 2048*128*4 = 1 MB
    prm.colpart2 = (float*) (ws + 25297408);   // 128*128*4 = 64 KB
    prm.colsum   = (float*) (ws + 25362944);

    prm.y_out  = (float*)d_out;
    prm.hp_out = (float*)d_out + N_NODES;
    prm.tr_out = (float*)d_out + N_NODES + (size_t)N_NODES * NHID;
    prm.E      = in_sizes[2] / 2;

    // --- pick the largest co-resident grid the occupancy allows -------------
    int bpc = 0;
    int nblk = 0;
    if (hipOccupancyMaxActiveBlocksPerMultiprocessor(&bpc, mega, NTHR, 0)
            == hipSuccess) {
        if      (bpc >= 8) nblk = 2048;   // 8192/2048 = 4 rows/block
        else if (bpc >= 4) nblk = 1024;   // 8 rows/block
        else if (bpc >= 2) nblk = 512;    // 16 rows/block
    }
    if (nblk > 0) {
        void* args[] = { (void*)&prm };
        if (hipLaunchCooperativeKernel(mega, dim3(nblk), dim3(NTHR),
                                       args, 0u, stream) == hipSuccess)
            return;
    }

    // ------------------------- fallback (round-4) --------------------------
    const size_t ZERO_BYTES = 8421376;
    zero_ws<<<2048, 256, 0, stream>>>((uint4*)ws, (int)(ZERO_BYTES / 16));
    gemm_mfma<<<dim3(4, 128), 256, 0, stream>>>(prm.x, prm.gcW, prm.gctW,
                                                prm.rep_preh);
    edge_pass1<<<(prm.E + 255) / 256, 256, 0, stream>>>(prm.ei, prm.E,
                                                        prm.bitmap, prm.cnt);
    scan_kernel<<<1, 1024, 0, stream>>>(prm.cnt, prm.rowptr);
    bitmap_extract<<<N_NODES, 64, 0, stream>>>(prm.bitmap, prm.rowptr,
                                               prm.colidx);
    aggregate_kernel<<<N_NODES, 256, 0, stream>>>(prm.rep_preh, prm.rowptr,
                                                  prm.colidx, prm.gcB, prm.gctB,
                                                  prm.avec, prm.rep, prm.rep_t_h,
                                                  prm.u, prm.v);
    colsum_kernel<<<256, 128, 0, stream>>>(prm.rep_t_h, prm.colpart);
    colsum_final<<<1, 128, 0, stream>>>(prm.colpart, prm.colsum);
    attention_kernel<<<N_NODES, 128, 0, stream>>>(prm.rowptr, prm.colidx,
                                                  prm.u, prm.v, prm.rep_t_h,
                                                  prm.rep, prm.colsum,
                                                  prm.hp_out);
    heads_kernel<<<N_NODES / 8, 128, 0, stream>>>(prm.hp_out, prm.rep, prm.t,
                                                  prm.ppW, prm.ppB, prm.pp2W, prm.pp2B,
                                                  prm.t00W, prm.t00B, prm.t10W, prm.t10B,
                                                  prm.t01W, prm.t01B, prm.t11W, prm.t11B,
                                                  prm.y_out, prm.tr_out);
}

// Round 8
// 131.223 us; speedup vs baseline: 7.4333x; 7.4333x over previous
//
#include <hip/hip_runtime.h>
#include <cstdint>
#include <cstddef>

#define N_NODES 8192
#define NFEAT   512
#define NHID    128

typedef unsigned short u16;
typedef __attribute__((ext_vector_type(8))) short bf16x8;
typedef __attribute__((ext_vector_type(4))) float f32x4;

__device__ inline u16 f2bf(float f) {
    unsigned int u = __float_as_uint(f);
    unsigned int r = (u + 0x7FFFu + ((u >> 16) & 1u)) >> 16;
    return (u16)r;
}
__device__ inline float bf2f(u16 h) {
    return __uint_as_float(((unsigned int)h) << 16);
}

// ---------------------------------------------------------------------------
// Workspace layout (bytes):
//   [0]          bitmap    : 8192*8192/8 = 8388608   (zeroed by init_gemm)
//   [8388608]    cnt       : 32768                    (zeroed)
//   [8421376]    rep_preh  : 8192*256*2 = 4194304    (bf16)
//   [12615680]   rep       : 8192*256*4 = 8388608    (f32)
//   [21004288]   rep_t_h   : 8192*128*2 = 2097152    (bf16)
//   [23101440]   u         : 32768
//   [23134208]   v         : 32768
//   [23166976]   rowptr    : 33280
//   [23200256]   colidx    : 1048576
//   [24248832]   colpart   : 256*128*4 = 131072
// ---------------------------------------------------------------------------

// ====== K1: blocks 0..511 GEMM (rep_preh = bf16(x@[gcW|gctW])), 512..2559
//        zero bitmap+cnt. Independent block ranges, no sync needed. =========
__global__ __launch_bounds__(256)
void init_gemm(const float* __restrict__ x,
               const float* __restrict__ gcW,
               const float* __restrict__ gctW,
               u16* __restrict__ rep_preh,
               uint4* __restrict__ zdst, int n16)
{
    const int tid = threadIdx.x;
    if (blockIdx.x >= 512) {
        const uint4 z = make_uint4(0u, 0u, 0u, 0u);
        for (int i = (blockIdx.x - 512) * 256 + tid; i < n16; i += 2048 * 256)
            zdst[i] = z;
        return;
    }
    const int tile = blockIdx.x;
    const int bx   = tile & 3;
    const int by   = tile >> 2;
    const int lane = tid & 63;
    const int wid  = tid >> 6;
    const int wr   = wid >> 1, wc = wid & 1;
    const float* W = (bx < 2) ? gcW : gctW;
    const int n0w  = (bx & 1) * 64;
    const int row0 = by * 64;

    __shared__ __align__(16) u16 Ash[64][40];
    __shared__ __align__(16) u16 Bsh[64][40];

    f32x4 acc[2][2];
#pragma unroll
    for (int i = 0; i < 2; ++i)
#pragma unroll
        for (int j = 0; j < 2; ++j) acc[i][j] = (f32x4){0.f, 0.f, 0.f, 0.f};

    const int sr = tid >> 2;
    const int sq = tid & 3;
    const int fr = lane & 15;
    const int fq = lane >> 4;

    for (int k0 = 0; k0 < NFEAT; k0 += 32) {
        {
            const float* src = x + (size_t)(row0 + sr) * NFEAT + k0 + sq * 8;
            const float4 a0 = *reinterpret_cast<const float4*>(src);
            const float4 a1 = *reinterpret_cast<const float4*>(src + 4);
            union { u16 s[8]; bf16x8 v; } pk;
            pk.s[0] = f2bf(a0.x); pk.s[1] = f2bf(a0.y);
            pk.s[2] = f2bf(a0.z); pk.s[3] = f2bf(a0.w);
            pk.s[4] = f2bf(a1.x); pk.s[5] = f2bf(a1.y);
            pk.s[6] = f2bf(a1.z); pk.s[7] = f2bf(a1.w);
            *reinterpret_cast<bf16x8*>(&Ash[sr][sq * 8]) = pk.v;
        }
        {
            const float* wsrc = W + (size_t)(k0 + sq * 8) * NHID + n0w + sr;
            union { u16 s[8]; bf16x8 v; } pk;
#pragma unroll
            for (int j = 0; j < 8; ++j)
                pk.s[j] = f2bf(wsrc[(size_t)j * NHID]);
            *reinterpret_cast<bf16x8*>(&Bsh[sr][sq * 8]) = pk.v;
        }
        __syncthreads();
        const bf16x8 a0 = *reinterpret_cast<const bf16x8*>(&Ash[wr * 32 + fr][fq * 8]);
        const bf16x8 a1 = *reinterpret_cast<const bf16x8*>(&Ash[wr * 32 + 16 + fr][fq * 8]);
        const bf16x8 b0 = *reinterpret_cast<const bf16x8*>(&Bsh[wc * 32 + fr][fq * 8]);
        const bf16x8 b1 = *reinterpret_cast<const bf16x8*>(&Bsh[wc * 32 + 16 + fr][fq * 8]);
        acc[0][0] = __builtin_amdgcn_mfma_f32_16x16x32_bf16(a0, b0, acc[0][0], 0, 0, 0);
        acc[0][1] = __builtin_amdgcn_mfma_f32_16x16x32_bf16(a0, b1, acc[0][1], 0, 0, 0);
        acc[1][0] = __builtin_amdgcn_mfma_f32_16x16x32_bf16(a1, b0, acc[1][0], 0, 0, 0);
        acc[1][1] = __builtin_amdgcn_mfma_f32_16x16x32_bf16(a1, b1, acc[1][1], 0, 0, 0);
        __syncthreads();
    }
    const int gr = row0 + wr * 32 + fq * 4;
    const int gc = bx * 64 + wc * 32 + fr;
#pragma unroll
    for (int mi = 0; mi < 2; ++mi)
#pragma unroll
        for (int ni = 0; ni < 2; ++ni)
#pragma unroll
            for (int i = 0; i < 4; ++i)
                rep_preh[(size_t)(gr + mi * 16 + i) * 256 + gc + ni * 16] =
                    f2bf(acc[mi][ni][i]);
}

// ============ K2: edge dedup (bitmap ownership + row counts) ================
__global__ void edge_pass1(const int* __restrict__ ei, int E,
                           unsigned int* __restrict__ bitmap,
                           int* __restrict__ cnt)
{
    const int e = blockIdx.x * blockDim.x + threadIdx.x;
    if (e >= E) return;
    const int s = ei[e];
    const int d = ei[E + e];
    const unsigned int idx  = (unsigned int)s * 8192u + (unsigned int)d;
    const unsigned int mask = 1u << (idx & 31u);
    const unsigned int old  = atomicOr(&bitmap[idx >> 5], mask);
    if ((old & mask) == 0u) atomicAdd(&cnt[s], 1);  // int add: deterministic
}

// ====== K3: per-block redundant scan of cnt + bitmap -> sorted colidx ======
// 256 blocks x 256 threads, 32 rows per block. Thread t sums chunk t (rows
// 32t..32t+31) -> block-wide inclusive scan -> block b's base = scan[b-1].
__global__ __launch_bounds__(256)
void scan_extract(const unsigned int* __restrict__ bitmap,
                  const int* __restrict__ cnt,
                  int* __restrict__ rowptr,
                  int* __restrict__ colidx)
{
    const int b   = blockIdx.x;
    const int tid = threadIdx.x;
    __shared__ int part[256];
    __shared__ int rowoff[33];

    int ssum = 0;
    const int cb = tid * 32;
#pragma unroll
    for (int j = 0; j < 32; ++j) ssum += cnt[cb + j];
    part[tid] = ssum;
    __syncthreads();
    for (int off = 1; off < 256; off <<= 1) {
        const int val = (tid >= off) ? part[tid - off] : 0;
        __syncthreads();
        part[tid] += val;
        __syncthreads();
    }
    if (tid == 0) {
        int off = (b == 0) ? 0 : part[b - 1];
        for (int j = 0; j < 32; ++j) {
            rowoff[j] = off;
            off += cnt[b * 32 + j];
        }
        rowoff[32] = off;
    }
    __syncthreads();
    if (tid < 32) rowptr[b * 32 + tid] = rowoff[tid];
    if (b == 255 && tid == 0) rowptr[N_NODES] = rowoff[32];

    // extract: 4 waves, wave wv handles local rows wv*8 .. wv*8+7
    const int wv = tid >> 6, lane = tid & 63;
    for (int k = 0; k < 8; ++k) {
        const int lrow = wv * 8 + k;
        const int row  = b * 32 + lrow;
        const uint4 w4 = *reinterpret_cast<const uint4*>(
            bitmap + (size_t)row * 256 + lane * 4);
        const int c = __popc(w4.x) + __popc(w4.y) + __popc(w4.z) + __popc(w4.w);
        int off = c;
        for (int d = 1; d < 64; d <<= 1) {
            const int n = __shfl_up(off, d, 64);
            if (lane >= d) off += n;
        }
        off -= c;
        int pos = rowoff[lrow] + off;
        const int base = lane * 128;
        unsigned int wvv[4] = {w4.x, w4.y, w4.z, w4.w};
#pragma unroll
        for (int j = 0; j < 4; ++j) {
            unsigned int bb = wvv[j];
            while (bb) {
                const int bit = __ffs(bb) - 1;
                colidx[pos++] = base + j * 32 + bit;
                bb &= bb - 1;
            }
        }
    }
}

// ====== K4: CSR aggregate (bf16 gather, 4-acc ILP) + bias + relu; u,v ======
__global__ __launch_bounds__(256)
void aggregate_kernel(const u16* __restrict__ rep_preh,
                      const int* __restrict__ rowptr,
                      const int* __restrict__ colidx,
                      const float* __restrict__ gcB,
                      const float* __restrict__ gctB,
                      const float* __restrict__ avec,
                      float* __restrict__ rep,
                      u16* __restrict__ rep_t_h,
                      float* __restrict__ u,
                      float* __restrict__ v)
{
    const int i   = blockIdx.x;
    const int tid = threadIdx.x;
    const int rp  = rowptr[i];
    const int rpe = rowptr[i + 1];

    float a0 = 0.f, a1 = 0.f, a2 = 0.f, a3 = 0.f;
    int q = rp;
    for (; q + 3 < rpe; q += 4) {
        const int c0 = colidx[q + 0], c1 = colidx[q + 1];
        const int c2 = colidx[q + 2], c3 = colidx[q + 3];
        a0 += bf2f(rep_preh[(size_t)c0 * 256 + tid]);
        a1 += bf2f(rep_preh[(size_t)c1 * 256 + tid]);
        a2 += bf2f(rep_preh[(size_t)c2 * 256 + tid]);
        a3 += bf2f(rep_preh[(size_t)c3 * 256 + tid]);
    }
    for (; q < rpe; ++q)
        a0 += bf2f(rep_preh[(size_t)colidx[q] * 256 + tid]);
    const float acc = (a0 + a1) + (a2 + a3);

    const float bias = (tid < 128) ? gcB[tid] : gctB[tid - 128];
    const float val  = fmaxf(acc + bias, 0.f);
    rep[(size_t)i * 256 + tid] = val;
    if (tid >= 128) rep_t_h[(size_t)i * 128 + tid - 128] = f2bf(val);

    // u,v: wave shuffle reduce + 4-word LDS fold (1 barrier)
    __shared__ float suw[4], svw[4];
    float pu = avec[tid] * val;
    float pv = avec[256 + tid] * val;
#pragma unroll
    for (int off = 32; off > 0; off >>= 1) {
        pu += __shfl_down(pu, off, 64);
        pv += __shfl_down(pv, off, 64);
    }
    const int lane = tid & 63, wid = tid >> 6;
    if (lane == 0) { suw[wid] = pu; svw[wid] = pv; }
    __syncthreads();
    if (tid == 0) {
        u[i] = (suw[0] + suw[1]) + (suw[2] + suw[3]);
        v[i] = (svw[0] + svw[1]) + (svw[2] + svw[3]);
    }
}

// ============ K5: colsum partials of rep_t (256 blocks x 32 rows) ===========
__global__ __launch_bounds__(128)
void colsum_kernel(const u16* __restrict__ rep_t_h, float* __restrict__ colpart)
{
    const int f  = threadIdx.x;
    const int b  = blockIdx.x;
    const int r0 = b * 32;
    float s0 = 0.f, s1 = 0.f, s2 = 0.f, s3 = 0.f;
    for (int r = 0; r < 32; r += 4) {
        s0 += bf2f(rep_t_h[(size_t)(r0 + r + 0) * 128 + f]);
        s1 += bf2f(rep_t_h[(size_t)(r0 + r + 1) * 128 + f]);
        s2 += bf2f(rep_t_h[(size_t)(r0 + r + 2) * 128 + f]);
        s3 += bf2f(rep_t_h[(size_t)(r0 + r + 3) * 128 + f]);
    }
    colpart[b * 128 + f] = (s0 + s1) + (s2 + s3);
}

// ====== K6: attention (8 rows/block, 2 at a time) + fused output heads =====
__global__ __launch_bounds__(256)
void attn_heads(const int* __restrict__ rowptr,
                const int* __restrict__ colidx,
                const float* __restrict__ u,
                const float* __restrict__ v,
                const u16* __restrict__ rep_t_h,
                const float* __restrict__ rep,
                const float* __restrict__ colpart,
                const int* __restrict__ t,
                const float* __restrict__ ppW,  const float* __restrict__ ppB,
                const float* __restrict__ pp2W, const float* __restrict__ pp2B,
                const float* __restrict__ t00W, const float* __restrict__ t00B,
                const float* __restrict__ t10W, const float* __restrict__ t10B,
                const float* __restrict__ t01W, const float* __restrict__ t01B,
                const float* __restrict__ t11W, const float* __restrict__ t11B,
                float* __restrict__ y_out,
                float* __restrict__ hp_out,
                float* __restrict__ tr_out)
{
    const int bid = blockIdx.x;
    const int tid = threadIdx.x;
    const int h   = tid >> 7, f = tid & 127;

    __shared__ float red[2][128];
    __shared__ float wsh[2][128];
    __shared__ int   csh[2][128];
    __shared__ float hs[8][128];
    __shared__ float ts[8][128];
    __shared__ float fin[2][2][4][4];

    // redundant deterministic colsum fold (256 partials, L2-hot)
    float c0 = 0.f, c1 = 0.f, c2 = 0.f, c3 = 0.f;
    for (int j = 0; j < 256; j += 4) {
        c0 += colpart[(j + 0) * 128 + f];
        c1 += colpart[(j + 1) * 128 + f];
        c2 += colpart[(j + 2) * 128 + f];
        c3 += colpart[(j + 3) * 128 + f];
    }
    const float csum = (c0 + c1) + (c2 + c3);

    for (int pr = 0; pr < 4; ++pr) {
        const int rbase = bid * 8 + pr * 2;
        const int rpA = rowptr[rbase];
        const int rpB = rowptr[rbase + 1];
        const int rpC = rowptr[rbase + 2];
        const int degA = rpB - rpA, degB = rpC - rpB;
        const int row  = rbase + h;
        const int rp   = h ? rpB : rpA;
        const int deg  = h ? degB : degA;
        const int maxdeg = max(degA, degB);
        const float ui = u[row];

        float mloc = -1e30f;
        for (int q = f; q < deg; q += 128)
            mloc = fmaxf(mloc, ui + v[colidx[rp + q]]);
        red[h][f] = mloc;
        __syncthreads();
#pragma unroll
        for (int s = 64; s > 0; s >>= 1) {
            if (f < s) red[h][f] = fmaxf(red[h][f], red[h][f + s]);
            __syncthreads();
        }
        const float m = fmaxf(red[h][0], 0.f);
        __syncthreads();
        const float e0 = expf(-m);

        float Zloc = 0.f;
        float pa0 = 0.f, pa1 = 0.f, pa2 = 0.f, pa3 = 0.f;
        const int rounds = (maxdeg + 127) >> 7;
        for (int b2 = 0; b2 < rounds; ++b2) {
            const int q = b2 * 128 + f;
            if (q < deg) {
                const int c = colidx[rp + q];
                csh[h][f] = c;
                const float w = expf(ui + v[c] - m);
                wsh[h][f] = w;
                Zloc += w;
            }
            __syncthreads();
            const int cnt2 = min(128, deg - b2 * 128);
            int q2 = 0;
            for (; q2 + 3 < cnt2; q2 += 4) {
                pa0 += (wsh[h][q2 + 0] - e0) * bf2f(rep_t_h[(size_t)csh[h][q2 + 0] * 128 + f]);
                pa1 += (wsh[h][q2 + 1] - e0) * bf2f(rep_t_h[(size_t)csh[h][q2 + 1] * 128 + f]);
                pa2 += (wsh[h][q2 + 2] - e0) * bf2f(rep_t_h[(size_t)csh[h][q2 + 2] * 128 + f]);
                pa3 += (wsh[h][q2 + 3] - e0) * bf2f(rep_t_h[(size_t)csh[h][q2 + 3] * 128 + f]);
            }
            for (; q2 < cnt2; ++q2)
                pa0 += (wsh[h][q2] - e0) * bf2f(rep_t_h[(size_t)csh[h][q2] * 128 + f]);
            __syncthreads();
        }
        const float acc = (pa0 + pa1) + (pa2 + pa3);
        red[h][f] = Zloc;
        __syncthreads();
#pragma unroll
        for (int s = 64; s > 0; s >>= 1) {
            if (f < s) red[h][f] += red[h][f + s];
            __syncthreads();
        }
        const float Z  = red[h][0] + (8192.f - (float)deg) * e0;
        const float hv = (acc + e0 * csum) / Z + rep[(size_t)row * 256 + f];
        hp_out[(size_t)row * 128 + f] = hv;
        hs[pr * 2 + h][f] = hv;
        __syncthreads();
    }

    // ---------------- fused heads: h handles rows h*4 .. h*4+3 -------------
    const int r0 = bid * 8;
#pragma unroll
    for (int r = 0; r < 4; ++r)
        ts[h * 4 + r][f] = rep[(size_t)(r0 + h * 4 + r) * 256 + 128 + f];
    __syncthreads();

    float a00[4] = {0, 0, 0, 0}, a10[4] = {0, 0, 0, 0}, app[4] = {0, 0, 0, 0};
    for (int k = 0; k < 128; ++k) {
        const float w00 = t00W[k * 128 + f];
        const float w10 = t10W[k * 128 + f];
        const float wpp = ppW [k * 128 + f];
#pragma unroll
        for (int r = 0; r < 4; ++r) {
            a00[r] += hs[h * 4 + r][k] * w00;
            a10[r] += hs[h * 4 + r][k] * w10;
            app[r] += ts[h * 4 + r][k] * wpp;
        }
    }
    const float b00 = t00B[f], b10 = t10B[f], bpp = ppB[f];
    const float w01 = t01W[f], w11 = t11W[f];
    const float w20 = pp2W[2 * f + 0], w21 = pp2W[2 * f + 1];
    const int lane = tid & 63, wih = (tid >> 6) & 1;
#pragma unroll
    for (int r = 0; r < 4; ++r) {
        float s0 = fmaxf(a00[r] + b00, 0.f) * w01;
        float s1 = fmaxf(a10[r] + b10, 0.f) * w11;
        const float hp2 = app[r] + bpp;
        float s2 = hp2 * w20;
        float s3 = hp2 * w21;
#pragma unroll
        for (int off = 32; off > 0; off >>= 1) {
            s0 += __shfl_down(s0, off, 64);
            s1 += __shfl_down(s1, off, 64);
            s2 += __shfl_down(s2, off, 64);
            s3 += __shfl_down(s3, off, 64);
        }
        if (lane == 0) {
            fin[h][wih][r][0] = s0;
            fin[h][wih][r][1] = s1;
            fin[h][wih][r][2] = s2;
            fin[h][wih][r][3] = s3;
        }
    }
    __syncthreads();
    if (tid < 8) {
        const int hh = tid >> 2, rr = tid & 3;
        const int node = r0 + hh * 4 + rr;
        const float y0 = fin[hh][0][rr][0] + fin[hh][1][rr][0] + t01B[0];
        const float y1 = fin[hh][0][rr][1] + fin[hh][1][rr][1] + t11B[0];
        y_out[node] = (t[node] > 0) ? y1 : y0;
        const float tr0 = fin[hh][0][rr][2] + fin[hh][1][rr][2] + pp2B[0];
        const float tr1 = fin[hh][0][rr][3] + fin[hh][1][rr][3] + pp2B[1];
        tr_out[node * 2 + 0] = 1.f / (1.f + expf(-tr0));
        tr_out[node * 2 + 1] = 1.f / (1.f + expf(-tr1));
    }
}

// ===========================================================================
extern "C" void kernel_launch(void* const* d_in, const int* in_sizes, int n_in,
                              void* d_out, int out_size, void* d_ws, size_t ws_size,
                              hipStream_t stream)
{
    const float* x    = (const float*)d_in[0];
    // d_in[1] = dense adj : intentionally unused
    const int*   ei   = (const int*)d_in[2];
    const int*   t    = (const int*)d_in[3];
    const float* gcW  = (const float*)d_in[4];
    const float* gcB  = (const float*)d_in[5];
    const float* gctW = (const float*)d_in[6];
    const float* gctB = (const float*)d_in[7];
    const float* avec = (const float*)d_in[8];
    const float* ppW  = (const float*)d_in[9];
    const float* ppB  = (const float*)d_in[10];
    const float* pp2W = (const float*)d_in[11];
    const float* pp2B = (const float*)d_in[12];
    const float* t00W = (const float*)d_in[13];
    const float* t00B = (const float*)d_in[14];
    const float* t10W = (const float*)d_in[15];
    const float* t10B = (const float*)d_in[16];
    const float* t01W = (const float*)d_in[17];
    const float* t01B = (const float*)d_in[18];
    const float* t11W = (const float*)d_in[19];
    const float* t11B = (const float*)d_in[20];

    const int E = in_sizes[2] / 2;

    char* ws = (char*)d_ws;
    unsigned int* bitmap   = (unsigned int*)(ws + 0);
    int*          cnt      = (int*)   (ws + 8388608);
    u16*          rep_preh = (u16*)   (ws + 8421376);
    float*        rep      = (float*) (ws + 12615680);
    u16*          rep_t_h  = (u16*)   (ws + 21004288);
    float*        u        = (float*) (ws + 23101440);
    float*        v        = (float*) (ws + 23134208);
    int*          rowptr   = (int*)   (ws + 23166976);
    int*          colidx   = (int*)   (ws + 23200256);
    float*        colpart  = (float*) (ws + 24248832);

    float* y_out  = (float*)d_out;
    float* hp_out = (float*)d_out + N_NODES;
    float* tr_out = (float*)d_out + N_NODES + (size_t)N_NODES * NHID;

    const int n16 = (8388608 + 32768) / 16;   // bitmap+cnt in uint4s

    init_gemm<<<2560, 256, 0, stream>>>(x, gcW, gctW, rep_preh,
                                        (uint4*)ws, n16);
    edge_pass1<<<(E + 255) / 256, 256, 0, stream>>>(ei, E, bitmap, cnt);
    scan_extract<<<256, 256, 0, stream>>>(bitmap, cnt, rowptr, colidx);
    aggregate_kernel<<<N_NODES, 256, 0, stream>>>(rep_preh, rowptr, colidx,
                                                  gcB, gctB, avec, rep,
                                                  rep_t_h, u, v);
    colsum_kernel<<<256, 128, 0, stream>>>(rep_t_h, colpart);
    attn_heads<<<N_NODES / 8, 256, 0, stream>>>(rowptr, colidx, u, v,
                                                rep_t_h, rep, colpart, t,
                                                ppW, ppB, pp2W, pp2B,
                                                t00W, t00B, t10W, t10B,
                                                t01W, t01B, t11W, t11B,
                                                y_out, hp_out, tr_out);
}